// Round 4
// baseline (345.631 us; speedup 1.0000x reference)
//
#include <hip/hip_runtime.h>

#define DT 0.001f
#define TAU_SYN_INV 200.0f
#define V_TH 1.0f

// Native vector type — __builtin_nontemporal_* requires a true vector, not
// HIP's struct-based float4.
typedef float vfloat4 __attribute__((ext_vector_type(4)));

// B,C,H,W = 16,64,128,128 ; N = 16777216 ; HW = 16384 elems = 4096 float4
#define EPT 2

__device__ __forceinline__ void lif_step(const vfloat4 v, const vfloat4 c,
                                         const vfloat4 xx, const float dt_tau,
                                         vfloat4& z, vfloat4& vn, vfloat4& in_)
{
    const float isyn_decay = 1.0f - DT * TAU_SYN_INV;   // 0.8
    #pragma unroll
    for (int k = 0; k < 4; ++k) {
        float vd = fmaf(dt_tau, c[k] - v[k], v[k]);
        bool s = vd > V_TH;
        z[k]   = s ? 1.0f : 0.0f;
        vn[k]  = s ? 0.0f : vd;
        in_[k] = fmaf(isyn_decay, c[k], xx[k]);
    }
}

__global__ __launch_bounds__(256) void trf_kernel(
    const vfloat4* __restrict__ x,
    const vfloat4* __restrict__ v0,
    const vfloat4* __restrict__ icur,
    const float*   __restrict__ ps,
    vfloat4* __restrict__ out_z,
    vfloat4* __restrict__ out_v,
    vfloat4* __restrict__ out_i,
    int n4)
{
    const int tid    = blockIdx.x * blockDim.x + threadIdx.x;
    const int stride = gridDim.x * blockDim.x;
    const int ia = tid;
    const int ib = tid + stride;

    if (ib < n4) {
        // Fast path (always taken at this shape): all six loads issued before
        // any compute/store — 6 loads in flight per thread.
        // Loads use the normal cached path (NT hint removed — A/B vs R2):
        // the 6.3 TB/s copy reference and 6.7 TB/s fills both use cached path.
        const vfloat4 va = v0[ia];
        const vfloat4 ca = icur[ia];
        const vfloat4 xa = x[ia];
        const vfloat4 vb = v0[ib];
        const vfloat4 cb = icur[ib];
        const vfloat4 xb = x[ib];

        // channel = (elem / (H*W)) % C = (i4 / 4096) % 64 — wave-uniform
        const float dta = DT * ps[(ia >> 12) & 63];
        const float dtb = DT * ps[(ib >> 12) & 63];

        vfloat4 za, vna, ina, zb, vnb, inb;
        lif_step(va, ca, xa, dta, za, vna, ina);
        lif_step(vb, cb, xb, dtb, zb, vnb, inb);

        // Stores stay nontemporal: no reuse, keep L3 clean for the next fill.
        __builtin_nontemporal_store(za,  &out_z[ia]);
        __builtin_nontemporal_store(vna, &out_v[ia]);
        __builtin_nontemporal_store(ina, &out_i[ia]);
        __builtin_nontemporal_store(zb,  &out_z[ib]);
        __builtin_nontemporal_store(vnb, &out_v[ib]);
        __builtin_nontemporal_store(inb, &out_i[ib]);
    } else if (ia < n4) {
        // Tail (never taken when grid*block*EPT == n4 exactly)
        const vfloat4 va = v0[ia];
        const vfloat4 ca = icur[ia];
        const vfloat4 xa = x[ia];
        const float dta = DT * ps[(ia >> 12) & 63];

        vfloat4 za, vna, ina;
        lif_step(va, ca, xa, dta, za, vna, ina);

        __builtin_nontemporal_store(za,  &out_z[ia]);
        __builtin_nontemporal_store(vna, &out_v[ia]);
        __builtin_nontemporal_store(ina, &out_i[ia]);
    }
}

extern "C" void kernel_launch(void* const* d_in, const int* in_sizes, int n_in,
                              void* d_out, int out_size, void* d_ws, size_t ws_size,
                              hipStream_t stream) {
    const float* x  = (const float*)d_in[0];
    const float* v0 = (const float*)d_in[1];
    const float* i0 = (const float*)d_in[2];
    const float* ps = (const float*)d_in[3];

    const int N  = in_sizes[0];          // 16777216
    const int n4 = N / 4;                // 4194304

    float* out = (float*)d_out;
    vfloat4* out_z = (vfloat4*)out;
    vfloat4* out_v = (vfloat4*)(out + (size_t)N);
    vfloat4* out_i = (vfloat4*)(out + 2 * (size_t)N);

    const int block = 256;
    const int grid  = (n4 + block * EPT - 1) / (block * EPT);  // 8192 blocks

    trf_kernel<<<grid, block, 0, stream>>>(
        (const vfloat4*)x, (const vfloat4*)v0, (const vfloat4*)i0, ps,
        out_z, out_v, out_i, n4);
}

// Round 5
// 327.118 us; speedup vs baseline: 1.0566x; 1.0566x over previous
//
#include <hip/hip_runtime.h>

#define DT 0.001f
#define TAU_SYN_INV 200.0f
#define V_TH 1.0f

// Native vector type — __builtin_nontemporal_* requires a true vector, not
// HIP's struct-based float4.
typedef float vfloat4 __attribute__((ext_vector_type(4)));

// B,C,H,W = 16,64,128,128 ; N = 16777216 ; HW = 16384 elems = 4096 float4
#define EPT 2

__device__ __forceinline__ void lif_step(const vfloat4 v, const vfloat4 c,
                                         const vfloat4 xx, const float dt_tau,
                                         vfloat4& z, vfloat4& vn, vfloat4& in_)
{
    const float isyn_decay = 1.0f - DT * TAU_SYN_INV;   // 0.8
    #pragma unroll
    for (int k = 0; k < 4; ++k) {
        float vd = fmaf(dt_tau, c[k] - v[k], v[k]);
        bool s = vd > V_TH;
        z[k]   = s ? 1.0f : 0.0f;
        vn[k]  = s ? 0.0f : vd;
        in_[k] = fmaf(isyn_decay, c[k], xx[k]);
    }
}

__global__ __launch_bounds__(256) void trf_kernel(
    const vfloat4* __restrict__ x,
    const vfloat4* __restrict__ v0,
    const vfloat4* __restrict__ icur,
    const float*   __restrict__ ps,
    vfloat4* __restrict__ out_z,
    vfloat4* __restrict__ out_v,
    vfloat4* __restrict__ out_i,
    int n4)
{
    const int tid    = blockIdx.x * blockDim.x + threadIdx.x;
    const int stride = gridDim.x * blockDim.x;
    const int ia = tid;
    const int ib = tid + stride;

    if (ib < n4) {
        // NT loads: measured better than cached loads (R2 wall 327.0 vs
        // R4 wall 345.6 / kernel 123 µs). Bypass L2/L3 allocation.
        const vfloat4 va = __builtin_nontemporal_load(&v0[ia]);
        const vfloat4 ca = __builtin_nontemporal_load(&icur[ia]);
        const vfloat4 xa = __builtin_nontemporal_load(&x[ia]);
        const vfloat4 vb = __builtin_nontemporal_load(&v0[ib]);
        const vfloat4 cb = __builtin_nontemporal_load(&icur[ib]);
        const vfloat4 xb = __builtin_nontemporal_load(&x[ib]);

        // channel = (elem / (H*W)) % C = (i4 / 4096) % 64 — wave-uniform
        const float dta = DT * ps[(ia >> 12) & 63];
        const float dtb = DT * ps[(ib >> 12) & 63];

        vfloat4 za, vna, ina, zb, vnb, inb;
        lif_step(va, ca, xa, dta, za, vna, ina);
        lif_step(vb, cb, xb, dtb, zb, vnb, inb);

        // A/B this round: PLAIN stores (harness fills sustain 6.6 TB/s with
        // the plain cached-write path; NT stores may bypass L2 write-combine).
        out_z[ia] = za;
        out_v[ia] = vna;
        out_i[ia] = ina;
        out_z[ib] = zb;
        out_v[ib] = vnb;
        out_i[ib] = inb;
    } else if (ia < n4) {
        // Tail (never taken when grid*block*EPT == n4 exactly)
        const vfloat4 va = __builtin_nontemporal_load(&v0[ia]);
        const vfloat4 ca = __builtin_nontemporal_load(&icur[ia]);
        const vfloat4 xa = __builtin_nontemporal_load(&x[ia]);
        const float dta = DT * ps[(ia >> 12) & 63];

        vfloat4 za, vna, ina;
        lif_step(va, ca, xa, dta, za, vna, ina);

        out_z[ia] = za;
        out_v[ia] = vna;
        out_i[ia] = ina;
    }
}

extern "C" void kernel_launch(void* const* d_in, const int* in_sizes, int n_in,
                              void* d_out, int out_size, void* d_ws, size_t ws_size,
                              hipStream_t stream) {
    const float* x  = (const float*)d_in[0];
    const float* v0 = (const float*)d_in[1];
    const float* i0 = (const float*)d_in[2];
    const float* ps = (const float*)d_in[3];

    const int N  = in_sizes[0];          // 16777216
    const int n4 = N / 4;                // 4194304

    float* out = (float*)d_out;
    vfloat4* out_z = (vfloat4*)out;
    vfloat4* out_v = (vfloat4*)(out + (size_t)N);
    vfloat4* out_i = (vfloat4*)(out + 2 * (size_t)N);

    const int block = 256;
    const int grid  = (n4 + block * EPT - 1) / (block * EPT);  // 8192 blocks

    trf_kernel<<<grid, block, 0, stream>>>(
        (const vfloat4*)x, (const vfloat4*)v0, (const vfloat4*)i0, ps,
        out_z, out_v, out_i, n4);
}

// Round 6
// 323.786 us; speedup vs baseline: 1.0675x; 1.0103x over previous
//
#include <hip/hip_runtime.h>

#define DT 0.001f
#define TAU_SYN_INV 200.0f
#define V_TH 1.0f

// Native vector type — __builtin_nontemporal_* requires a true vector, not
// HIP's struct-based float4.
typedef float vfloat4 __attribute__((ext_vector_type(4)));

// B,C,H,W = 16,64,128,128 ; N = 16777216 ; HW = 16384 elems = 4096 float4
// EPT=4, block-contiguous: each block owns 256*4 = 1024 consecutive float4
// (16 KB) per stream; a wave issues 4 consecutive 1 KB loads per stream
// (same-DRAM-page bursts), 12 loads batched before any store.
#define EPT 4

__device__ __forceinline__ void lif_step(const vfloat4 v, const vfloat4 c,
                                         const vfloat4 xx, const float dt_tau,
                                         vfloat4& z, vfloat4& vn, vfloat4& in_)
{
    const float isyn_decay = 1.0f - DT * TAU_SYN_INV;   // 0.8
    #pragma unroll
    for (int k = 0; k < 4; ++k) {
        float vd = fmaf(dt_tau, c[k] - v[k], v[k]);
        bool s = vd > V_TH;
        z[k]   = s ? 1.0f : 0.0f;
        vn[k]  = s ? 0.0f : vd;
        in_[k] = fmaf(isyn_decay, c[k], xx[k]);
    }
}

__global__ __launch_bounds__(256) void trf_kernel(
    const vfloat4* __restrict__ x,
    const vfloat4* __restrict__ v0,
    const vfloat4* __restrict__ icur,
    const float*   __restrict__ ps,
    vfloat4* __restrict__ out_z,
    vfloat4* __restrict__ out_v,
    vfloat4* __restrict__ out_i,
    int n4)
{
    // Block-contiguous indexing: i_k = blockBase + k*256 + tid
    const int base = blockIdx.x * (blockDim.x * EPT) + threadIdx.x;

    if (base + 3 * 256 < n4) {
        int i0i = base;
        int i1i = base + 256;
        int i2i = base + 512;
        int i3i = base + 768;

        // 12 NT loads batched — loads measured faster NT (R4 A/B);
        // stores NT-vs-plain neutral (R5 A/B), keep NT.
        const vfloat4 v0a = __builtin_nontemporal_load(&v0[i0i]);
        const vfloat4 v0b = __builtin_nontemporal_load(&v0[i1i]);
        const vfloat4 v0c = __builtin_nontemporal_load(&v0[i2i]);
        const vfloat4 v0d = __builtin_nontemporal_load(&v0[i3i]);
        const vfloat4 c0a = __builtin_nontemporal_load(&icur[i0i]);
        const vfloat4 c0b = __builtin_nontemporal_load(&icur[i1i]);
        const vfloat4 c0c = __builtin_nontemporal_load(&icur[i2i]);
        const vfloat4 c0d = __builtin_nontemporal_load(&icur[i3i]);
        const vfloat4 x0a = __builtin_nontemporal_load(&x[i0i]);
        const vfloat4 x0b = __builtin_nontemporal_load(&x[i1i]);
        const vfloat4 x0c = __builtin_nontemporal_load(&x[i2i]);
        const vfloat4 x0d = __builtin_nontemporal_load(&x[i3i]);

        // channel = (i4 / 4096) % 64 — wave-uniform
        const float dta = DT * ps[(i0i >> 12) & 63];
        const float dtb = DT * ps[(i1i >> 12) & 63];
        const float dtc = DT * ps[(i2i >> 12) & 63];
        const float dtd = DT * ps[(i3i >> 12) & 63];

        vfloat4 za, vna, ina, zb, vnb, inb, zc, vnc, inc_, zd, vnd, ind;
        lif_step(v0a, c0a, x0a, dta, za, vna, ina);
        lif_step(v0b, c0b, x0b, dtb, zb, vnb, inb);
        lif_step(v0c, c0c, x0c, dtc, zc, vnc, inc_);
        lif_step(v0d, c0d, x0d, dtd, zd, vnd, ind);

        __builtin_nontemporal_store(za,   &out_z[i0i]);
        __builtin_nontemporal_store(zb,   &out_z[i1i]);
        __builtin_nontemporal_store(zc,   &out_z[i2i]);
        __builtin_nontemporal_store(zd,   &out_z[i3i]);
        __builtin_nontemporal_store(vna,  &out_v[i0i]);
        __builtin_nontemporal_store(vnb,  &out_v[i1i]);
        __builtin_nontemporal_store(vnc,  &out_v[i2i]);
        __builtin_nontemporal_store(vnd,  &out_v[i3i]);
        __builtin_nontemporal_store(ina,  &out_i[i0i]);
        __builtin_nontemporal_store(inb,  &out_i[i1i]);
        __builtin_nontemporal_store(inc_, &out_i[i2i]);
        __builtin_nontemporal_store(ind,  &out_i[i3i]);
    } else {
        // Tail (never taken at this shape: 4096*1024 == n4 exactly)
        #pragma unroll
        for (int k = 0; k < EPT; ++k) {
            int i = base + k * 256;
            if (i < n4) {
                const vfloat4 v  = __builtin_nontemporal_load(&v0[i]);
                const vfloat4 c  = __builtin_nontemporal_load(&icur[i]);
                const vfloat4 xx = __builtin_nontemporal_load(&x[i]);
                const float dt_tau = DT * ps[(i >> 12) & 63];
                vfloat4 z, vn, in_;
                lif_step(v, c, xx, dt_tau, z, vn, in_);
                __builtin_nontemporal_store(z,   &out_z[i]);
                __builtin_nontemporal_store(vn,  &out_v[i]);
                __builtin_nontemporal_store(in_, &out_i[i]);
            }
        }
    }
}

extern "C" void kernel_launch(void* const* d_in, const int* in_sizes, int n_in,
                              void* d_out, int out_size, void* d_ws, size_t ws_size,
                              hipStream_t stream) {
    const float* x  = (const float*)d_in[0];
    const float* v0 = (const float*)d_in[1];
    const float* i0 = (const float*)d_in[2];
    const float* ps = (const float*)d_in[3];

    const int N  = in_sizes[0];          // 16777216
    const int n4 = N / 4;                // 4194304

    float* out = (float*)d_out;
    vfloat4* out_z = (vfloat4*)out;
    vfloat4* out_v = (vfloat4*)(out + (size_t)N);
    vfloat4* out_i = (vfloat4*)(out + 2 * (size_t)N);

    const int block = 256;
    const int grid  = (n4 + block * EPT - 1) / (block * EPT);  // 4096 blocks

    trf_kernel<<<grid, block, 0, stream>>>(
        (const vfloat4*)x, (const vfloat4*)v0, (const vfloat4*)i0, ps,
        out_z, out_v, out_i, n4);
}

// Round 7
// 321.805 us; speedup vs baseline: 1.0740x; 1.0062x over previous
//
#include <hip/hip_runtime.h>

#define DT 0.001f
#define TAU_SYN_INV 200.0f
#define V_TH 1.0f

// Native vector type — __builtin_nontemporal_* requires a true vector, not
// HIP's struct-based float4.
typedef float vfloat4 __attribute__((ext_vector_type(4)));

// B,C,H,W = 16,64,128,128 ; N = 16777216 ; HW = 16384 elems = 4096 float4
// EPT=8, block-contiguous: each block owns 256*8 = 2048 consecutive float4
// (32 KB) per stream; a wave issues 8 consecutive 1 KB loads per stream
// (long same-DRAM-page runs), all 24 loads batched before any store,
// then stream-major 32 KB store bursts. Grid = 2048 blocks.
#define EPT 8

__device__ __forceinline__ void lif_step(const vfloat4 v, const vfloat4 c,
                                         const vfloat4 xx, const float dt_tau,
                                         vfloat4& z, vfloat4& vn, vfloat4& in_)
{
    const float isyn_decay = 1.0f - DT * TAU_SYN_INV;   // 0.8
    #pragma unroll
    for (int k = 0; k < 4; ++k) {
        float vd = fmaf(dt_tau, c[k] - v[k], v[k]);
        bool s = vd > V_TH;
        z[k]   = s ? 1.0f : 0.0f;
        vn[k]  = s ? 0.0f : vd;
        in_[k] = fmaf(isyn_decay, c[k], xx[k]);
    }
}

__global__ __launch_bounds__(256) void trf_kernel(
    const vfloat4* __restrict__ x,
    const vfloat4* __restrict__ v0,
    const vfloat4* __restrict__ icur,
    const float*   __restrict__ ps,
    vfloat4* __restrict__ out_z,
    vfloat4* __restrict__ out_v,
    vfloat4* __restrict__ out_i,
    int n4)
{
    // Block-contiguous indexing: i_k = blockBase + k*256 + tid
    const int base = blockIdx.x * (blockDim.x * EPT) + threadIdx.x;

    if (base + (EPT - 1) * 256 < n4) {
        vfloat4 vv[EPT], cc[EPT], xxv[EPT];

        // 24 NT loads batched, stream-major (v0 burst, icur burst, x burst).
        // All compile-time indices (full unroll) — no scratch.
        #pragma unroll
        for (int k = 0; k < EPT; ++k)
            vv[k] = __builtin_nontemporal_load(&v0[base + k * 256]);
        #pragma unroll
        for (int k = 0; k < EPT; ++k)
            cc[k] = __builtin_nontemporal_load(&icur[base + k * 256]);
        #pragma unroll
        for (int k = 0; k < EPT; ++k)
            xxv[k] = __builtin_nontemporal_load(&x[base + k * 256]);

        // channel = (i4 / 4096) % 64 — wave-uniform
        float dt[EPT];
        #pragma unroll
        for (int k = 0; k < EPT; ++k)
            dt[k] = DT * ps[((base + k * 256) >> 12) & 63];

        vfloat4 z[EPT], vn[EPT], in_[EPT];
        #pragma unroll
        for (int k = 0; k < EPT; ++k)
            lif_step(vv[k], cc[k], xxv[k], dt[k], z[k], vn[k], in_[k]);

        // Stream-major store bursts: 32 KB contiguous per stream per block.
        #pragma unroll
        for (int k = 0; k < EPT; ++k)
            __builtin_nontemporal_store(z[k],   &out_z[base + k * 256]);
        #pragma unroll
        for (int k = 0; k < EPT; ++k)
            __builtin_nontemporal_store(vn[k],  &out_v[base + k * 256]);
        #pragma unroll
        for (int k = 0; k < EPT; ++k)
            __builtin_nontemporal_store(in_[k], &out_i[base + k * 256]);
    } else {
        // Tail (never taken at this shape: 2048*2048 == n4 exactly)
        #pragma unroll
        for (int k = 0; k < EPT; ++k) {
            int i = base + k * 256;
            if (i < n4) {
                const vfloat4 v  = __builtin_nontemporal_load(&v0[i]);
                const vfloat4 c  = __builtin_nontemporal_load(&icur[i]);
                const vfloat4 xx = __builtin_nontemporal_load(&x[i]);
                const float dt_tau = DT * ps[(i >> 12) & 63];
                vfloat4 zz, vnn, inn;
                lif_step(v, c, xx, dt_tau, zz, vnn, inn);
                __builtin_nontemporal_store(zz,  &out_z[i]);
                __builtin_nontemporal_store(vnn, &out_v[i]);
                __builtin_nontemporal_store(inn, &out_i[i]);
            }
        }
    }
}

extern "C" void kernel_launch(void* const* d_in, const int* in_sizes, int n_in,
                              void* d_out, int out_size, void* d_ws, size_t ws_size,
                              hipStream_t stream) {
    const float* x  = (const float*)d_in[0];
    const float* v0 = (const float*)d_in[1];
    const float* i0 = (const float*)d_in[2];
    const float* ps = (const float*)d_in[3];

    const int N  = in_sizes[0];          // 16777216
    const int n4 = N / 4;                // 4194304

    float* out = (float*)d_out;
    vfloat4* out_z = (vfloat4*)out;
    vfloat4* out_v = (vfloat4*)(out + (size_t)N);
    vfloat4* out_i = (vfloat4*)(out + 2 * (size_t)N);

    const int block = 256;
    const int grid  = (n4 + block * EPT - 1) / (block * EPT);  // 2048 blocks

    trf_kernel<<<grid, block, 0, stream>>>(
        (const vfloat4*)x, (const vfloat4*)v0, (const vfloat4*)i0, ps,
        out_z, out_v, out_i, n4);
}